// Round 1
// 3363.206 us; speedup vs baseline: 1.5385x; 1.5385x over previous
//
#include <hip/hip_runtime.h>

#define BT 1024   // batch
#define TT 512    // total timesteps

__device__ __forceinline__ float sig_(float x) { return 1.f / (1.f + __expf(-x)); }
__device__ __forceinline__ float th_(float x)  { return 1.f - 2.f / (1.f + __expf(2.f * x)); }

// ---------------------------------------------------------------------------
// pre[R][n] = sum_k Arow(R)[k] * W[n][k] + bih[n] + bhh[n]
// (unchanged from previous round — not the bottleneck)
// ---------------------------------------------------------------------------
template <int K, int KPAD, int N, bool XMODE>
__global__ __launch_bounds__(256) void gemm_pre(
    const float* __restrict__ A, const float* __restrict__ W,
    const float* __restrict__ bih, const float* __restrict__ bhh,
    float* __restrict__ out, int t0)
{
    __shared__ float As[128][KPAD];
    __shared__ __align__(16) float Bs[K][64];
    const int tid = threadIdx.x;
    const int n0 = blockIdx.x * 64;
    const int Rbase = blockIdx.y * 128;
    const int NQ = K / 4;

    for (int ii = tid; ii < 128 * NQ; ii += 256) {
        int r = ii / NQ, q = ii % NQ;
        const float* src;
        if (XMODE) {
            int b  = (blockIdx.y & 7) * 128 + r;
            int tl = blockIdx.y >> 3;
            src = A + ((size_t)b * TT + (t0 + tl)) * K;
        } else {
            src = A + (size_t)(Rbase + r) * K;
        }
        float4 v = *(const float4*)(src + q * 4);
        As[r][q * 4 + 0] = v.x; As[r][q * 4 + 1] = v.y;
        As[r][q * 4 + 2] = v.z; As[r][q * 4 + 3] = v.w;
    }
    for (int ii = tid; ii < 64 * NQ; ii += 256) {
        int n = ii & 63, kq = ii >> 6;
        float4 v = make_float4(0.f, 0.f, 0.f, 0.f);
        if (n0 + n < N) v = *(const float4*)(W + (size_t)(n0 + n) * K + kq * 4);
        Bs[kq * 4 + 0][n] = v.x; Bs[kq * 4 + 1][n] = v.y;
        Bs[kq * 4 + 2][n] = v.z; Bs[kq * 4 + 3][n] = v.w;
    }
    __syncthreads();

    const int tx = tid & 15, ty = tid >> 4;
    float acc[8][4];
#pragma unroll
    for (int i = 0; i < 8; i++)
#pragma unroll
        for (int jj = 0; jj < 4; jj++) acc[i][jj] = 0.f;

#pragma unroll 4
    for (int k = 0; k < K; k++) {
        float4 bv = *(const float4*)&Bs[k][tx * 4];
#pragma unroll
        for (int i = 0; i < 8; i++) {
            float a = As[ty * 8 + i][k];
            acc[i][0] += a * bv.x; acc[i][1] += a * bv.y;
            acc[i][2] += a * bv.z; acc[i][3] += a * bv.w;
        }
    }
    int n = n0 + tx * 4;
    if (n < N) {
        float4 bias;
        bias.x = bih[n] + bhh[n];     bias.y = bih[n + 1] + bhh[n + 1];
        bias.z = bih[n + 2] + bhh[n + 2]; bias.w = bih[n + 3] + bhh[n + 3];
#pragma unroll
        for (int i = 0; i < 8; i++) {
            size_t R = (size_t)Rbase + ty * 8 + i;
            float4 o;
            o.x = acc[i][0] + bias.x; o.y = acc[i][1] + bias.y;
            o.z = acc[i][2] + bias.z; o.w = acc[i][3] + bias.w;
            *(float4*)(out + R * N + n) = o;
        }
    }
}

// ---------------------------------------------------------------------------
// rec1 v3: 256 WGs x 512 thr (8 waves -> 2 waves/SIMD), 4 batch elems/WG.
// R0 THEORY: v2 was latency-bound (13k cyc/timestep vs ~2k issue-bound) —
// VGPR_Count=128 < the 200 regs its weight arrays needed => spill + no regs
// to batch LDS reads, all on 1 wave/SIMD. v3: each compute thread (tid<400:
// j=tid%100, kq=tid/100) owns a 4-row (one per gate) x quarter-k weight
// slice: w[4][7] float4 = 112 VGPRs. Partial dots per k-quarter go to LDS
// gbuf[kq][gate][b][j]; update threads sum the 4 partials.
//   - weights fit registers with slack under __launch_bounds__(512,2)
//     (8 waves/WG = exactly 2 waves/EU -> 256-VGPR budget, one WG/CU)
//   - per-wave critical path: 7 LDS-read rounds (was 25), 448 FMA (was 800)
//   - FMA:DS = 16:1 (was 4:1) -> DS pipe cannot bound
// k-quarter float4 ranges: kq0=[0,7), kq1=[7,13), kq2=[13,19), kq3=[19,25);
// uniform 7-iteration loop with zero-padded 7th weight f4 (kq>0) and
// zero-padded hs rows (104 floats) so kq3's f4 #25 reads zeros.
// ---------------------------------------------------------------------------
__global__ __launch_bounds__(512, 2) void rec1(
    const float* __restrict__ pre,   // [Tc][1024][400]
    const float* __restrict__ Whh,   // [400][100]
    float* __restrict__ hseq,        // [Tc][1024][100]
    float* __restrict__ cst,         // [1024][100]
    int Tc, int first)
{
    __shared__ __align__(16) float hs[4][104];      // 416B stride, 16B-aligned, pad zeroed
    __shared__ __align__(16) float pres[2][1600];
    __shared__ float gbuf[4 * 4 * 4 * 100];         // [kq][gate][b][j] = 6400 floats
    const int tid = threadIdx.x;
    const int b0 = blockIdx.x * 4;

    const bool comp = tid < 400;
    const int j  = tid % 100;
    const int kq = tid / 100;                       // 0..3 (only comp threads use it)
    const int koff = (kq == 0) ? 0 : (6 * kq + 1);  // {0,7,13,19} float4 offset

    float4 w[4][7];                                 // 4 gate-rows x quarter-k: 112 VGPRs
    if (comp) {
#pragma unroll
        for (int g = 0; g < 4; g++) {
            const float4* W4 = (const float4*)(Whh + (size_t)(g * 100 + j) * 100);
#pragma unroll
            for (int q = 0; q < 6; q++) w[g][q] = W4[koff + q];
            w[g][6] = (kq == 0) ? W4[6] : make_float4(0.f, 0.f, 0.f, 0.f);
        }
    }

    // state: update threads = tid<400 (ub=batch, uj=unit)
    const int ub = tid / 100, uj = tid % 100;
    float c = 0.f;
    if (comp) {
        float h = 0.f;
        if (!first) {
            h = hseq[((size_t)(Tc - 1) * BT + b0 + ub) * 100 + uj];
            c = cst[(size_t)(b0 + ub) * 100 + uj];
        }
        hs[ub][uj] = h;
    } else if (tid < 416) {                          // zero hs pad floats 100..103 x 4 rows
        int p = tid - 400;
        hs[p >> 2][100 + (p & 3)] = 0.f;
    }
    if (comp) {                                      // stage pres[0]: 400 float4
        const float4* p4 = (const float4*)(pre + (size_t)b0 * 400);
        ((float4*)pres[0])[tid] = p4[tid];
    }
    __syncthreads();

    int cur = 0;
    for (int t = 0; t < Tc; t++) {
        // prefetch t+1 pre slice into registers (hidden under the k-loop)
        int tn = (t + 1 < Tc) ? (t + 1) : t;
        float4 pf0 = make_float4(0.f, 0.f, 0.f, 0.f);
        if (comp) {
            const float4* p4 = (const float4*)(pre + (size_t)tn * BT * 400 + (size_t)b0 * 400);
            pf0 = p4[tid];
        }

        if (comp) {
            float acc[4][4];                         // [gate][batch]
#pragma unroll
            for (int g = 0; g < 4; g++)
#pragma unroll
                for (int b = 0; b < 4; b++) acc[g][b] = 0.f;
            const float4* h0 = (const float4*)hs[0];
            const float4* h1 = (const float4*)hs[1];
            const float4* h2 = (const float4*)hs[2];
            const float4* h3 = (const float4*)hs[3];
#pragma unroll
            for (int q = 0; q < 7; q++) {
                int f = koff + q;
                float4 v0 = h0[f], v1 = h1[f], v2 = h2[f], v3 = h3[f];
#pragma unroll
                for (int g = 0; g < 4; g++) {
                    float4 wq = w[g][q];
                    acc[g][0] += wq.x*v0.x + wq.y*v0.y + wq.z*v0.z + wq.w*v0.w;
                    acc[g][1] += wq.x*v1.x + wq.y*v1.y + wq.z*v1.z + wq.w*v1.w;
                    acc[g][2] += wq.x*v2.x + wq.y*v2.y + wq.z*v2.z + wq.w*v2.w;
                    acc[g][3] += wq.x*v3.x + wq.y*v3.y + wq.z*v3.z + wq.w*v3.w;
                }
            }
#pragma unroll
            for (int g = 0; g < 4; g++)
#pragma unroll
                for (int b = 0; b < 4; b++)
                    gbuf[((kq * 4 + g) * 4 + b) * 100 + j] = acc[g][b];
        }
        __syncthreads();   // gbuf ready; everyone done reading hs & pres[cur]

        if (comp) {        // update: sum 4 k-quarter partials per gate + pre + activations
            const float* pb = pres[cur];
            float s0 = 0.f, s1 = 0.f, s2 = 0.f, s3 = 0.f;
#pragma unroll
            for (int q = 0; q < 4; q++) {
                int base = (q * 4) * 4 * 100;
                s0 += gbuf[base + (0 * 4 + ub) * 100 + uj];
                s1 += gbuf[base + (1 * 4 + ub) * 100 + uj];
                s2 += gbuf[base + (2 * 4 + ub) * 100 + uj];
                s3 += gbuf[base + (3 * 4 + ub) * 100 + uj];
            }
            float xi = s0 + pb[ub * 400 + uj];
            float xf = s1 + pb[ub * 400 + 100 + uj];
            float xg = s2 + pb[ub * 400 + 200 + uj];
            float xo = s3 + pb[ub * 400 + 300 + uj];
            float ii = sig_(xi), ff = sig_(xf), gg = th_(xg), oo = sig_(xo);
            c = ff * c + ii * gg;
            float h = oo * th_(c);
            hs[ub][uj] = h;
            hseq[((size_t)t * BT + b0 + ub) * 100 + uj] = h;
            // commit prefetched pre into the next buffer
            ((float4*)pres[cur ^ 1])[tid] = pf0;
        }
        __syncthreads();   // hs & pres[nxt] ready
        cur ^= 1;
    }
    if (comp) cst[(size_t)(b0 + ub) * 100 + uj] = c;
}

// ---------------------------------------------------------------------------
// rec2 v3: layer-2 (H=50, 200 rows), same restructure. Compute threads
// tid<400: bh=tid/200 picks 2 of the 4 batches, then kq=(tid%200)/50,
// j=tid%50. Each owns 4 gate-rows x quarter-k: w[4][4] float4 = 64 VGPRs
// (scalar-loaded: Whh2 rows are 200B so float4 would misalign on odd rows).
// k=50 -> f4 quarters kq0=[0,4), kq1=[4,7), kq2=[7,10), kq3=[10,13) with
// zero-pad (w component zeroed when k>=kend); hs rows padded to 64 floats.
// ---------------------------------------------------------------------------
__global__ __launch_bounds__(512, 2) void rec2(
    const float* __restrict__ pre2,  // [Tc][1024][200]
    const float* __restrict__ Whh,   // [200][50]
    float* __restrict__ cst, float* __restrict__ hst,  // [1024][50]
    float* __restrict__ out,         // [1024][50]
    int Tc, int first)
{
    __shared__ __align__(16) float hs[4][64];       // 256B stride, pad floats 50..63 zeroed
    __shared__ __align__(16) float pres[2][800];
    __shared__ float gbuf[4 * 4 * 4 * 50];          // [kq][gate][b][j] = 3200 floats
    const int tid = threadIdx.x;
    const int b0 = blockIdx.x * 4;

    const bool comp = tid < 400;
    const int bh  = tid / 200;                      // batch half: {0,1} or {2,3}
    const int rem = tid % 200;
    const int kq  = rem / 50;
    const int j   = rem % 50;
    const int kst = (kq == 0) ? 0 : (3 * kq + 1);   // {0,4,7,10} float4 offset
    const int kend = (kq == 3) ? 50 : (16 + kq * 12); // {16,28,40,50} float bound

    float4 w[4][4];                                 // 4 gate-rows x quarter-k: 64 VGPRs
    if (comp) {
#pragma unroll
        for (int g = 0; g < 4; g++) {
            const float* W = Whh + (size_t)(g * 50 + j) * 50;
#pragma unroll
            for (int q = 0; q < 4; q++) {
                int k = (kst + q) * 4;
                w[g][q].x = (k + 0 < kend) ? W[k + 0] : 0.f;
                w[g][q].y = (k + 1 < kend) ? W[k + 1] : 0.f;
                w[g][q].z = (k + 2 < kend) ? W[k + 2] : 0.f;
                w[g][q].w = (k + 3 < kend) ? W[k + 3] : 0.f;
            }
        }
    }

    // update threads: tid<200 (ub=batch, uj=unit), keep c & hlast in regs
    const bool upd = tid < 200;
    const int ub = tid / 50, uj = tid % 50;
    float c = 0.f, hlast = 0.f;
    if (upd) {
        float h = 0.f;
        if (!first) {
            h = hst[(size_t)(b0 + ub) * 50 + uj];
            c = cst[(size_t)(b0 + ub) * 50 + uj];
        }
        hs[ub][uj] = h;
        hlast = h;
    } else if (tid < 256) {                          // zero hs pads: 4 rows x floats 50..63
        int p = tid - 200;
        hs[p / 14][50 + p % 14] = 0.f;
    }
    if (upd) {                                       // stage pres[0]: 200 float4
        const float4* p4 = (const float4*)(pre2 + (size_t)b0 * 200);
        ((float4*)pres[0])[tid] = p4[tid];
    }
    __syncthreads();

    int cur = 0;
    for (int t = 0; t < Tc; t++) {
        int tn = (t + 1 < Tc) ? (t + 1) : t;
        float4 pf0 = make_float4(0.f, 0.f, 0.f, 0.f);
        if (upd) {
            const float4* p4 = (const float4*)(pre2 + (size_t)tn * BT * 200 + (size_t)b0 * 200);
            pf0 = p4[tid];
        }

        if (comp) {
            float acc[4][2];                         // [gate][batch-in-half]
#pragma unroll
            for (int g = 0; g < 4; g++) { acc[g][0] = 0.f; acc[g][1] = 0.f; }
            const float4* hA = (const float4*)hs[bh * 2];
            const float4* hB = (const float4*)hs[bh * 2 + 1];
#pragma unroll
            for (int q = 0; q < 4; q++) {
                int f = kst + q;
                float4 vA = hA[f], vB = hB[f];
#pragma unroll
                for (int g = 0; g < 4; g++) {
                    float4 wq = w[g][q];
                    acc[g][0] += wq.x*vA.x + wq.y*vA.y + wq.z*vA.z + wq.w*vA.w;
                    acc[g][1] += wq.x*vB.x + wq.y*vB.y + wq.z*vB.z + wq.w*vB.w;
                }
            }
#pragma unroll
            for (int g = 0; g < 4; g++) {
                gbuf[((kq * 4 + g) * 4 + bh * 2 + 0) * 50 + j] = acc[g][0];
                gbuf[((kq * 4 + g) * 4 + bh * 2 + 1) * 50 + j] = acc[g][1];
            }
        }
        __syncthreads();

        if (upd) {
            const float* pb = pres[cur];
            float s0 = 0.f, s1 = 0.f, s2 = 0.f, s3 = 0.f;
#pragma unroll
            for (int q = 0; q < 4; q++) {
                int base = (q * 4) * 4 * 50;
                s0 += gbuf[base + (0 * 4 + ub) * 50 + uj];
                s1 += gbuf[base + (1 * 4 + ub) * 50 + uj];
                s2 += gbuf[base + (2 * 4 + ub) * 50 + uj];
                s3 += gbuf[base + (3 * 4 + ub) * 50 + uj];
            }
            float xi = s0 + pb[ub * 200 + uj];
            float xf = s1 + pb[ub * 200 + 50 + uj];
            float xg = s2 + pb[ub * 200 + 100 + uj];
            float xo = s3 + pb[ub * 200 + 150 + uj];
            float ii = sig_(xi), ff = sig_(xf), gg = th_(xg), oo = sig_(xo);
            c = ff * c + ii * gg;
            float h = oo * th_(c);
            hs[ub][uj] = h;
            hlast = h;
            ((float4*)pres[cur ^ 1])[tid] = pf0;
        }
        __syncthreads();
        cur ^= 1;
    }
    if (upd) {
        cst[(size_t)(b0 + ub) * 50 + uj] = c;
        hst[(size_t)(b0 + ub) * 50 + uj] = hlast;
        out[(size_t)(b0 + ub) * 50 + uj] = hlast;
    }
}

// ---------------------------------------------------------------------------
extern "C" void kernel_launch(void* const* d_in, const int* in_sizes, int n_in,
                              void* d_out, int out_size, void* d_ws, size_t ws_size,
                              hipStream_t stream)
{
    const float* x    = (const float*)d_in[0];
    const float* Wih1 = (const float*)d_in[1];
    const float* Whh1 = (const float*)d_in[2];
    const float* bih1 = (const float*)d_in[3];
    const float* bhh1 = (const float*)d_in[4];
    const float* Wih2 = (const float*)d_in[5];
    const float* Whh2 = (const float*)d_in[6];
    const float* bih2 = (const float*)d_in[7];
    const float* bhh2 = (const float*)d_in[8];
    float* out = (float*)d_out;
    float* ws  = (float*)d_ws;

    int Tc = 64;
    auto need = [](int tc) -> size_t {
        return ((size_t)tc * 1024 * (400 + 100 + 200) +
                (size_t)1024 * 100 + (size_t)1024 * 50 * 2) * sizeof(float);
    };
    while (Tc > 1 && need(Tc) > ws_size) Tc >>= 1;

    float* pre1 = ws;
    float* h1s  = pre1 + (size_t)Tc * 1024 * 400;
    float* pre2 = h1s  + (size_t)Tc * 1024 * 100;
    float* c1   = pre2 + (size_t)Tc * 1024 * 200;
    float* c2   = c1 + 1024 * 100;
    float* h2st = c2 + 1024 * 50;

    const int nch = TT / Tc;
    for (int ch = 0; ch < nch; ch++) {
        int t0 = ch * Tc;
        gemm_pre<80, 81, 400, true ><<<dim3(7, Tc * 8), 256, 0, stream>>>(
            x, Wih1, bih1, bhh1, pre1, t0);
        rec1<<<dim3(256), dim3(512), 0, stream>>>(pre1, Whh1, h1s, c1, Tc, ch == 0 ? 1 : 0);
        gemm_pre<100, 101, 200, false><<<dim3(4, Tc * 8), 256, 0, stream>>>(
            h1s, Wih2, bih2, bhh2, pre2, 0);
        rec2<<<dim3(256), dim3(512), 0, stream>>>(pre2, Whh2, c2, h2st, out, Tc, ch == 0 ? 1 : 0);
    }
}

// Round 2
// 2927.970 us; speedup vs baseline: 1.7672x; 1.1486x over previous
//
#include <hip/hip_runtime.h>

#define BT 1024   // batch
#define TT 512    // total timesteps

__device__ __forceinline__ float sig_(float x) { return 1.f / (1.f + __expf(-x)); }
__device__ __forceinline__ float th_(float x)  { return 1.f - 2.f / (1.f + __expf(2.f * x)); }

// ---------------------------------------------------------------------------
// pre[R][n] = sum_k Arow(R)[k] * W[n][k] + bih[n] + bhh[n]
// (unchanged — not yet shown as a bottleneck in counters)
// ---------------------------------------------------------------------------
template <int K, int KPAD, int N, bool XMODE>
__global__ __launch_bounds__(256) void gemm_pre(
    const float* __restrict__ A, const float* __restrict__ W,
    const float* __restrict__ bih, const float* __restrict__ bhh,
    float* __restrict__ out, int t0)
{
    __shared__ float As[128][KPAD];
    __shared__ __align__(16) float Bs[K][64];
    const int tid = threadIdx.x;
    const int n0 = blockIdx.x * 64;
    const int Rbase = blockIdx.y * 128;
    const int NQ = K / 4;

    for (int ii = tid; ii < 128 * NQ; ii += 256) {
        int r = ii / NQ, q = ii % NQ;
        const float* src;
        if (XMODE) {
            int b  = (blockIdx.y & 7) * 128 + r;
            int tl = blockIdx.y >> 3;
            src = A + ((size_t)b * TT + (t0 + tl)) * K;
        } else {
            src = A + (size_t)(Rbase + r) * K;
        }
        float4 v = *(const float4*)(src + q * 4);
        As[r][q * 4 + 0] = v.x; As[r][q * 4 + 1] = v.y;
        As[r][q * 4 + 2] = v.z; As[r][q * 4 + 3] = v.w;
    }
    for (int ii = tid; ii < 64 * NQ; ii += 256) {
        int n = ii & 63, kq = ii >> 6;
        float4 v = make_float4(0.f, 0.f, 0.f, 0.f);
        if (n0 + n < N) v = *(const float4*)(W + (size_t)(n0 + n) * K + kq * 4);
        Bs[kq * 4 + 0][n] = v.x; Bs[kq * 4 + 1][n] = v.y;
        Bs[kq * 4 + 2][n] = v.z; Bs[kq * 4 + 3][n] = v.w;
    }
    __syncthreads();

    const int tx = tid & 15, ty = tid >> 4;
    float acc[8][4];
#pragma unroll
    for (int i = 0; i < 8; i++)
#pragma unroll
        for (int jj = 0; jj < 4; jj++) acc[i][jj] = 0.f;

#pragma unroll 4
    for (int k = 0; k < K; k++) {
        float4 bv = *(const float4*)&Bs[k][tx * 4];
#pragma unroll
        for (int i = 0; i < 8; i++) {
            float a = As[ty * 8 + i][k];
            acc[i][0] += a * bv.x; acc[i][1] += a * bv.y;
            acc[i][2] += a * bv.z; acc[i][3] += a * bv.w;
        }
    }
    int n = n0 + tx * 4;
    if (n < N) {
        float4 bias;
        bias.x = bih[n] + bhh[n];     bias.y = bih[n + 1] + bhh[n + 1];
        bias.z = bih[n + 2] + bhh[n + 2]; bias.w = bih[n + 3] + bhh[n + 3];
#pragma unroll
        for (int i = 0; i < 8; i++) {
            size_t R = (size_t)Rbase + ty * 8 + i;
            float4 o;
            o.x = acc[i][0] + bias.x; o.y = acc[i][1] + bias.y;
            o.z = acc[i][2] + bias.z; o.w = acc[i][3] + bias.w;
            *(float4*)(out + R * N + n) = o;
        }
    }
}

// ---------------------------------------------------------------------------
// rec1 v4: 512 WGs x 512 thr, 2 batch elems/WG -> 2 WGs/CU = 4 waves/SIMD.
// R1 THEORY: v3 was 4.9x off the 1250-cyc/timestep FMA floor. Levers:
//  (a) exact k-fifth split: k=100 = 5 x 5xfloat4, ZERO pad waste (v3: +12%),
//      weights w[4][5] = 80 VGPRs;
//  (b) __launch_bounds__(512,4) forces VGPR<=128 -> 2 WGs/CU resident
//      (need ~120: 80 w + 8 acc + 8 ldtmp + 4 pf + misc). 4 waves/SIMD
//      hides barrier/LDS latency (other WG fills stalls);
//  (c) explicit fmaf chains: 4 VALU per 4 MACs (expression form compiled
//      to mul+fma+fma+fma+add = 5/4).
// comp threads tid<500: j=tid%100, kq=tid/100 own 4 gate-rows x k-fifth;
// partials -> gbuf[kq][gate][b][j]; upd threads tid<200 sum 5 partials.
// Every wave issues the full k-loop (balanced); update phase lands one
// wave per SIMD (waves 0-3).
// DO NOT change min-waves to 1 (R1-R7 container-failure lesson, prev session).
// ---------------------------------------------------------------------------
__global__ __launch_bounds__(512, 4) void rec1(
    const float* __restrict__ pre,   // [Tc][1024][400]
    const float* __restrict__ Whh,   // [400][100]
    float* __restrict__ hseq,        // [Tc][1024][100]
    float* __restrict__ cst,         // [1024][100]
    int Tc, int first)
{
    __shared__ __align__(16) float hs[2][100];      // 25 float4 per row, exact
    __shared__ __align__(16) float pres[2][800];
    __shared__ float gbuf[5 * 4 * 2 * 100];         // [kq][gate][b][j] = 4000 floats
    const int tid = threadIdx.x;
    const int b0 = blockIdx.x * 2;

    const bool comp = tid < 500;
    const int j  = tid % 100;
    const int kq = tid / 100;                       // 0..4 (comp threads)

    float4 w[4][5];                                 // 4 gate-rows x k-fifth: 80 VGPRs
    if (comp) {
#pragma unroll
        for (int g = 0; g < 4; g++) {
            const float4* W4 = (const float4*)(Whh + (size_t)(g * 100 + j) * 100);
#pragma unroll
            for (int q = 0; q < 5; q++) w[g][q] = W4[kq * 5 + q];
        }
    }

    const bool upd = tid < 200;
    const int ub = tid / 100, uj = tid % 100;       // batch-in-WG, unit
    float c = 0.f;
    if (upd) {
        float h = 0.f;
        if (!first) {
            h = hseq[((size_t)(Tc - 1) * BT + b0 + ub) * 100 + uj];
            c = cst[(size_t)(b0 + ub) * 100 + uj];
        }
        hs[ub][uj] = h;
        // stage pres[0]: 800 contiguous floats = 200 float4
        ((float4*)pres[0])[tid] = ((const float4*)(pre + (size_t)b0 * 400))[tid];
    }
    __syncthreads();

    int cur = 0;
    for (int t = 0; t < Tc; t++) {
        // prefetch t+1 pre slice into registers (hidden under the k-loop)
        int tn = (t + 1 < Tc) ? (t + 1) : t;
        float4 pf0;
        if (upd)
            pf0 = ((const float4*)(pre + (size_t)tn * BT * 400 + (size_t)b0 * 400))[tid];

        if (comp) {
            float acc[4][2];                         // [gate][batch]
#pragma unroll
            for (int g = 0; g < 4; g++) { acc[g][0] = 0.f; acc[g][1] = 0.f; }
            const float4* h0 = (const float4*)hs[0];
            const float4* h1 = (const float4*)hs[1];
#pragma unroll
            for (int q = 0; q < 5; q++) {
                int f = kq * 5 + q;
                float4 v0 = h0[f], v1 = h1[f];
#pragma unroll
                for (int g = 0; g < 4; g++) {
                    float4 wq = w[g][q];
                    acc[g][0] = fmaf(wq.x, v0.x, acc[g][0]);
                    acc[g][0] = fmaf(wq.y, v0.y, acc[g][0]);
                    acc[g][0] = fmaf(wq.z, v0.z, acc[g][0]);
                    acc[g][0] = fmaf(wq.w, v0.w, acc[g][0]);
                    acc[g][1] = fmaf(wq.x, v1.x, acc[g][1]);
                    acc[g][1] = fmaf(wq.y, v1.y, acc[g][1]);
                    acc[g][1] = fmaf(wq.z, v1.z, acc[g][1]);
                    acc[g][1] = fmaf(wq.w, v1.w, acc[g][1]);
                }
            }
#pragma unroll
            for (int g = 0; g < 4; g++) {
                gbuf[((kq * 4 + g) * 2 + 0) * 100 + j] = acc[g][0];
                gbuf[((kq * 4 + g) * 2 + 1) * 100 + j] = acc[g][1];
            }
        }
        __syncthreads();   // gbuf ready; everyone done reading hs & pres[cur]

        if (upd) {         // sum 5 k-fifth partials per gate + pre + activations
            const float* pb = pres[cur];
            float s0 = 0.f, s1 = 0.f, s2 = 0.f, s3 = 0.f;
#pragma unroll
            for (int q = 0; q < 5; q++) {
                int base = q * 800;                  // (q*4)*2*100
                s0 += gbuf[base + (0 * 2 + ub) * 100 + uj];
                s1 += gbuf[base + (1 * 2 + ub) * 100 + uj];
                s2 += gbuf[base + (2 * 2 + ub) * 100 + uj];
                s3 += gbuf[base + (3 * 2 + ub) * 100 + uj];
            }
            float xi = s0 + pb[ub * 400 + uj];
            float xf = s1 + pb[ub * 400 + 100 + uj];
            float xg = s2 + pb[ub * 400 + 200 + uj];
            float xo = s3 + pb[ub * 400 + 300 + uj];
            float ii = sig_(xi), ff = sig_(xf), gg = th_(xg), oo = sig_(xo);
            c = ff * c + ii * gg;
            float h = oo * th_(c);
            hs[ub][uj] = h;
            hseq[((size_t)t * BT + b0 + ub) * 100 + uj] = h;
            ((float4*)pres[cur ^ 1])[tid] = pf0;     // commit prefetched pre
        }
        __syncthreads();   // hs & pres[nxt] ready
        cur ^= 1;
    }
    if (upd) cst[(size_t)(b0 + ub) * 100 + uj] = c;
}

// ---------------------------------------------------------------------------
// rec2 v4: layer-2 (H=50, 200 rows), same restructure. 512 WGs x 256 thr,
// 2 batches/WG -> 2 WGs/CU. Exact k-fifth: k=50 = 5 x 5xfloat2 (Whh2 rows
// are 200B so float2 is the widest always-aligned load; 50*4B % 8 == 0 so
// hs rows stay float2-aligned too). comp tid<250: j=tid%50, kq=tid/50 owns
// 4 gate-rows x 10 k: w[4][5] float2 = 40 VGPRs. upd tid<100.
// ---------------------------------------------------------------------------
__global__ __launch_bounds__(256, 4) void rec2(
    const float* __restrict__ pre2,  // [Tc][1024][200]
    const float* __restrict__ Whh,   // [200][50]
    float* __restrict__ cst, float* __restrict__ hst,  // [1024][50]
    float* __restrict__ out,         // [1024][50]
    int Tc, int first)
{
    __shared__ __align__(16) float hs[2][50];       // 25 float2 per row, exact
    __shared__ __align__(16) float pres[2][400];
    __shared__ float gbuf[5 * 4 * 2 * 50];          // [kq][gate][b][j] = 2000 floats
    const int tid = threadIdx.x;
    const int b0 = blockIdx.x * 2;

    const bool comp = tid < 250;
    const int j  = tid % 50;
    const int kq = tid / 50;                        // 0..4 (comp threads)

    float2 w[4][5];                                 // 4 gate-rows x k-fifth: 40 VGPRs
    if (comp) {
#pragma unroll
        for (int g = 0; g < 4; g++) {
            const float2* W2 = (const float2*)(Whh + (size_t)(g * 50 + j) * 50);
#pragma unroll
            for (int q = 0; q < 5; q++) w[g][q] = W2[kq * 5 + q];
        }
    }

    const bool upd = tid < 100;
    const int ub = tid / 50, uj = tid % 50;
    float c = 0.f, hlast = 0.f;
    if (upd) {
        float h = 0.f;
        if (!first) {
            h = hst[(size_t)(b0 + ub) * 50 + uj];
            c = cst[(size_t)(b0 + ub) * 50 + uj];
        }
        hs[ub][uj] = h;
        hlast = h;
        // stage pres[0]: 400 contiguous floats = 100 float4
        ((float4*)pres[0])[tid] = ((const float4*)(pre2 + (size_t)b0 * 200))[tid];
    }
    __syncthreads();

    int cur = 0;
    for (int t = 0; t < Tc; t++) {
        int tn = (t + 1 < Tc) ? (t + 1) : t;
        float4 pf0;
        if (upd)
            pf0 = ((const float4*)(pre2 + (size_t)tn * BT * 200 + (size_t)b0 * 200))[tid];

        if (comp) {
            float acc[4][2];
#pragma unroll
            for (int g = 0; g < 4; g++) { acc[g][0] = 0.f; acc[g][1] = 0.f; }
            const float2* hA = (const float2*)hs[0];
            const float2* hB = (const float2*)hs[1];
#pragma unroll
            for (int q = 0; q < 5; q++) {
                int f = kq * 5 + q;
                float2 v0 = hA[f], v1 = hB[f];
#pragma unroll
                for (int g = 0; g < 4; g++) {
                    float2 wq = w[g][q];
                    acc[g][0] = fmaf(wq.x, v0.x, acc[g][0]);
                    acc[g][0] = fmaf(wq.y, v0.y, acc[g][0]);
                    acc[g][1] = fmaf(wq.x, v1.x, acc[g][1]);
                    acc[g][1] = fmaf(wq.y, v1.y, acc[g][1]);
                }
            }
#pragma unroll
            for (int g = 0; g < 4; g++) {
                gbuf[((kq * 4 + g) * 2 + 0) * 50 + j] = acc[g][0];
                gbuf[((kq * 4 + g) * 2 + 1) * 50 + j] = acc[g][1];
            }
        }
        __syncthreads();

        if (upd) {
            const float* pb = pres[cur];
            float s0 = 0.f, s1 = 0.f, s2 = 0.f, s3 = 0.f;
#pragma unroll
            for (int q = 0; q < 5; q++) {
                int base = q * 400;                  // (q*4)*2*50
                s0 += gbuf[base + (0 * 2 + ub) * 50 + uj];
                s1 += gbuf[base + (1 * 2 + ub) * 50 + uj];
                s2 += gbuf[base + (2 * 2 + ub) * 50 + uj];
                s3 += gbuf[base + (3 * 2 + ub) * 50 + uj];
            }
            float xi = s0 + pb[ub * 200 + uj];
            float xf = s1 + pb[ub * 200 + 50 + uj];
            float xg = s2 + pb[ub * 200 + 100 + uj];
            float xo = s3 + pb[ub * 200 + 150 + uj];
            float ii = sig_(xi), ff = sig_(xf), gg = th_(xg), oo = sig_(xo);
            c = ff * c + ii * gg;
            float h = oo * th_(c);
            hs[ub][uj] = h;
            hlast = h;
            ((float4*)pres[cur ^ 1])[tid] = pf0;
        }
        __syncthreads();
        cur ^= 1;
    }
    if (upd) {
        cst[(size_t)(b0 + ub) * 50 + uj] = c;
        hst[(size_t)(b0 + ub) * 50 + uj] = hlast;
        out[(size_t)(b0 + ub) * 50 + uj] = hlast;
    }
}

// ---------------------------------------------------------------------------
extern "C" void kernel_launch(void* const* d_in, const int* in_sizes, int n_in,
                              void* d_out, int out_size, void* d_ws, size_t ws_size,
                              hipStream_t stream)
{
    const float* x    = (const float*)d_in[0];
    const float* Wih1 = (const float*)d_in[1];
    const float* Whh1 = (const float*)d_in[2];
    const float* bih1 = (const float*)d_in[3];
    const float* bhh1 = (const float*)d_in[4];
    const float* Wih2 = (const float*)d_in[5];
    const float* Whh2 = (const float*)d_in[6];
    const float* bih2 = (const float*)d_in[7];
    const float* bhh2 = (const float*)d_in[8];
    float* out = (float*)d_out;
    float* ws  = (float*)d_ws;

    int Tc = 64;
    auto need = [](int tc) -> size_t {
        return ((size_t)tc * 1024 * (400 + 100 + 200) +
                (size_t)1024 * 100 + (size_t)1024 * 50 * 2) * sizeof(float);
    };
    while (Tc > 1 && need(Tc) > ws_size) Tc >>= 1;

    float* pre1 = ws;
    float* h1s  = pre1 + (size_t)Tc * 1024 * 400;
    float* pre2 = h1s  + (size_t)Tc * 1024 * 100;
    float* c1   = pre2 + (size_t)Tc * 1024 * 200;
    float* c2   = c1 + 1024 * 100;
    float* h2st = c2 + 1024 * 50;

    const int nch = TT / Tc;
    for (int ch = 0; ch < nch; ch++) {
        int t0 = ch * Tc;
        gemm_pre<80, 81, 400, true ><<<dim3(7, Tc * 8), 256, 0, stream>>>(
            x, Wih1, bih1, bhh1, pre1, t0);
        rec1<<<dim3(512), dim3(512), 0, stream>>>(pre1, Whh1, h1s, c1, Tc, ch == 0 ? 1 : 0);
        gemm_pre<100, 101, 200, false><<<dim3(4, Tc * 8), 256, 0, stream>>>(
            h1s, Wih2, bih2, bhh2, pre2, 0);
        rec2<<<dim3(512), dim3(256), 0, stream>>>(pre2, Whh2, c2, h2st, out, Tc, ch == 0 ? 1 : 0);
    }
}

// Round 3
// 2579.657 us; speedup vs baseline: 2.0059x; 1.1350x over previous
//
#include <hip/hip_runtime.h>

#define BT 1024   // batch
#define TT 512    // total timesteps

__device__ __forceinline__ float sig_(float x) { return 1.f / (1.f + __expf(-x)); }
__device__ __forceinline__ float th_(float x)  { return 1.f - 2.f / (1.f + __expf(2.f * x)); }

// ---------------------------------------------------------------------------
// gemm_pre v2. R2 THEORY: v1 was latency-bound at 20% of FMA peak —
// 9 LDS issues (8 scalar, 4-way-conflicted) per 32 FMA, and 60.5KB LDS
// capped residency at 2 WGs/CU (2 waves/SIMD). Fixes:
//  (a) 4-k inner step, float4 As reads: per 4k = 8 b128 As + 4 b128 Bs
//      + 128 FMA (LDS:FMA 1:10.7, was ~1:3.5);
//  (b) K split in two staged halves (80=40+40, 100=52+48): LDS 30.7/39.9KB
//      -> 4 WGs/CU = 4 waves/SIMD (__launch_bounds__(256,4), ~100 VGPR);
//  (c) strided row ownership r = ty + 16*i (not ty*8+i): wave's 4 ty-groups
//      read disjoint bank quartets ({8r}/{20r} mod 32 distinct for
//      consecutive r) -> conflict-free b128; row stride 40/52 floats keeps
//      16B alignment. No KPAD+1 padding needed.
// ---------------------------------------------------------------------------
template <int KS, int KPAD, int KH, int N, bool XMODE>
__device__ __forceinline__ void gp_stage(
    const float* __restrict__ A, const float* __restrict__ W,
    float (&As)[128][KPAD], float (&Bs)[KPAD][64],
    int tid, int n0, int by, int t0, int k0)
{
    constexpr int NQH = KH / 4;
#pragma unroll
    for (int ii = tid; ii < 128 * NQH; ii += 256) {
        int r = ii / NQH, q = ii % NQH;
        const float* src;
        if (XMODE) {
            int b  = (by & 7) * 128 + r;
            int tl = by >> 3;
            src = A + ((size_t)b * TT + (t0 + tl)) * KS;
        } else {
            src = A + (size_t)(by * 128 + r) * KS;
        }
        float4 v = *(const float4*)(src + k0 + q * 4);
        As[r][q * 4 + 0] = v.x; As[r][q * 4 + 1] = v.y;
        As[r][q * 4 + 2] = v.z; As[r][q * 4 + 3] = v.w;
    }
#pragma unroll
    for (int ii = tid; ii < 64 * NQH; ii += 256) {
        int n = ii & 63, kq = ii >> 6;
        float4 v = make_float4(0.f, 0.f, 0.f, 0.f);
        if (n0 + n < N) v = *(const float4*)(W + (size_t)(n0 + n) * KS + k0 + kq * 4);
        Bs[kq * 4 + 0][n] = v.x; Bs[kq * 4 + 1][n] = v.y;
        Bs[kq * 4 + 2][n] = v.z; Bs[kq * 4 + 3][n] = v.w;
    }
}

template <int KPAD, int KH>
__device__ __forceinline__ void gp_compute(
    const float (&As)[128][KPAD], const float (&Bs)[KPAD][64],
    float (&acc)[8][4], int tx, int ty)
{
    for (int kk = 0; kk < KH; kk += 4) {
        float4 bv0 = *(const float4*)&Bs[kk + 0][tx * 4];
        float4 bv1 = *(const float4*)&Bs[kk + 1][tx * 4];
        float4 bv2 = *(const float4*)&Bs[kk + 2][tx * 4];
        float4 bv3 = *(const float4*)&Bs[kk + 3][tx * 4];
#pragma unroll
        for (int i = 0; i < 8; i++) {
            float4 av = *(const float4*)&As[ty + 16 * i][kk];
            acc[i][0] = fmaf(av.x, bv0.x, acc[i][0]);
            acc[i][0] = fmaf(av.y, bv1.x, acc[i][0]);
            acc[i][0] = fmaf(av.z, bv2.x, acc[i][0]);
            acc[i][0] = fmaf(av.w, bv3.x, acc[i][0]);
            acc[i][1] = fmaf(av.x, bv0.y, acc[i][1]);
            acc[i][1] = fmaf(av.y, bv1.y, acc[i][1]);
            acc[i][1] = fmaf(av.z, bv2.y, acc[i][1]);
            acc[i][1] = fmaf(av.w, bv3.y, acc[i][1]);
            acc[i][2] = fmaf(av.x, bv0.z, acc[i][2]);
            acc[i][2] = fmaf(av.y, bv1.z, acc[i][2]);
            acc[i][2] = fmaf(av.z, bv2.z, acc[i][2]);
            acc[i][2] = fmaf(av.w, bv3.z, acc[i][2]);
            acc[i][3] = fmaf(av.x, bv0.w, acc[i][3]);
            acc[i][3] = fmaf(av.y, bv1.w, acc[i][3]);
            acc[i][3] = fmaf(av.z, bv2.w, acc[i][3]);
            acc[i][3] = fmaf(av.w, bv3.w, acc[i][3]);
        }
    }
}

template <int KS, int KPAD, int KH0, int N, bool XMODE>
__global__ __launch_bounds__(256, 4) void gemm_pre(
    const float* __restrict__ A, const float* __restrict__ W,
    const float* __restrict__ bih, const float* __restrict__ bhh,
    float* __restrict__ out, int t0)
{
    constexpr int KH1 = KS - KH0;
    __shared__ __align__(16) float As[128][KPAD];
    __shared__ __align__(16) float Bs[KPAD][64];
    const int tid = threadIdx.x;
    const int n0 = blockIdx.x * 64;
    const int by = blockIdx.y;
    const int Rbase = by * 128;
    const int tx = tid & 15, ty = tid >> 4;

    float acc[8][4];
#pragma unroll
    for (int i = 0; i < 8; i++)
#pragma unroll
        for (int j = 0; j < 4; j++) acc[i][j] = 0.f;

    gp_stage<KS, KPAD, KH0, N, XMODE>(A, W, As, Bs, tid, n0, by, t0, 0);
    __syncthreads();
    gp_compute<KPAD, KH0>(As, Bs, acc, tx, ty);
    __syncthreads();
    gp_stage<KS, KPAD, KH1, N, XMODE>(A, W, As, Bs, tid, n0, by, t0, KH0);
    __syncthreads();
    gp_compute<KPAD, KH1>(As, Bs, acc, tx, ty);

    int n = n0 + tx * 4;
    if (n < N) {
        float4 bias;
        bias.x = bih[n] + bhh[n];         bias.y = bih[n + 1] + bhh[n + 1];
        bias.z = bih[n + 2] + bhh[n + 2]; bias.w = bih[n + 3] + bhh[n + 3];
#pragma unroll
        for (int i = 0; i < 8; i++) {
            size_t R = (size_t)Rbase + ty + 16 * i;
            float4 o;
            o.x = acc[i][0] + bias.x; o.y = acc[i][1] + bias.y;
            o.z = acc[i][2] + bias.z; o.w = acc[i][3] + bias.w;
            *(float4*)(out + R * N + n) = o;
        }
    }
}

// ---------------------------------------------------------------------------
// rec1 v4 (unchanged this round): 512 WGs x 512 thr, 2 batch elems/WG.
// DO NOT change min-waves to 1 (R1-R7 container-failure lesson, prev session).
// ---------------------------------------------------------------------------
__global__ __launch_bounds__(512, 4) void rec1(
    const float* __restrict__ pre,   // [Tc][1024][400]
    const float* __restrict__ Whh,   // [400][100]
    float* __restrict__ hseq,        // [Tc][1024][100]
    float* __restrict__ cst,         // [1024][100]
    int Tc, int first)
{
    __shared__ __align__(16) float hs[2][100];
    __shared__ __align__(16) float pres[2][800];
    __shared__ float gbuf[5 * 4 * 2 * 100];
    const int tid = threadIdx.x;
    const int b0 = blockIdx.x * 2;

    const bool comp = tid < 500;
    const int j  = tid % 100;
    const int kq = tid / 100;

    float4 w[4][5];
    if (comp) {
#pragma unroll
        for (int g = 0; g < 4; g++) {
            const float4* W4 = (const float4*)(Whh + (size_t)(g * 100 + j) * 100);
#pragma unroll
            for (int q = 0; q < 5; q++) w[g][q] = W4[kq * 5 + q];
        }
    }

    const bool upd = tid < 200;
    const int ub = tid / 100, uj = tid % 100;
    float c = 0.f;
    if (upd) {
        float h = 0.f;
        if (!first) {
            h = hseq[((size_t)(Tc - 1) * BT + b0 + ub) * 100 + uj];
            c = cst[(size_t)(b0 + ub) * 100 + uj];
        }
        hs[ub][uj] = h;
        ((float4*)pres[0])[tid] = ((const float4*)(pre + (size_t)b0 * 400))[tid];
    }
    __syncthreads();

    int cur = 0;
    for (int t = 0; t < Tc; t++) {
        int tn = (t + 1 < Tc) ? (t + 1) : t;
        float4 pf0;
        if (upd)
            pf0 = ((const float4*)(pre + (size_t)tn * BT * 400 + (size_t)b0 * 400))[tid];

        if (comp) {
            float acc[4][2];
#pragma unroll
            for (int g = 0; g < 4; g++) { acc[g][0] = 0.f; acc[g][1] = 0.f; }
            const float4* h0 = (const float4*)hs[0];
            const float4* h1 = (const float4*)hs[1];
#pragma unroll
            for (int q = 0; q < 5; q++) {
                int f = kq * 5 + q;
                float4 v0 = h0[f], v1 = h1[f];
#pragma unroll
                for (int g = 0; g < 4; g++) {
                    float4 wq = w[g][q];
                    acc[g][0] = fmaf(wq.x, v0.x, acc[g][0]);
                    acc[g][0] = fmaf(wq.y, v0.y, acc[g][0]);
                    acc[g][0] = fmaf(wq.z, v0.z, acc[g][0]);
                    acc[g][0] = fmaf(wq.w, v0.w, acc[g][0]);
                    acc[g][1] = fmaf(wq.x, v1.x, acc[g][1]);
                    acc[g][1] = fmaf(wq.y, v1.y, acc[g][1]);
                    acc[g][1] = fmaf(wq.z, v1.z, acc[g][1]);
                    acc[g][1] = fmaf(wq.w, v1.w, acc[g][1]);
                }
            }
#pragma unroll
            for (int g = 0; g < 4; g++) {
                gbuf[((kq * 4 + g) * 2 + 0) * 100 + j] = acc[g][0];
                gbuf[((kq * 4 + g) * 2 + 1) * 100 + j] = acc[g][1];
            }
        }
        __syncthreads();

        if (upd) {
            const float* pb = pres[cur];
            float s0 = 0.f, s1 = 0.f, s2 = 0.f, s3 = 0.f;
#pragma unroll
            for (int q = 0; q < 5; q++) {
                int base = q * 800;
                s0 += gbuf[base + (0 * 2 + ub) * 100 + uj];
                s1 += gbuf[base + (1 * 2 + ub) * 100 + uj];
                s2 += gbuf[base + (2 * 2 + ub) * 100 + uj];
                s3 += gbuf[base + (3 * 2 + ub) * 100 + uj];
            }
            float xi = s0 + pb[ub * 400 + uj];
            float xf = s1 + pb[ub * 400 + 100 + uj];
            float xg = s2 + pb[ub * 400 + 200 + uj];
            float xo = s3 + pb[ub * 400 + 300 + uj];
            float ii = sig_(xi), ff = sig_(xf), gg = th_(xg), oo = sig_(xo);
            c = ff * c + ii * gg;
            float h = oo * th_(c);
            hs[ub][uj] = h;
            hseq[((size_t)t * BT + b0 + ub) * 100 + uj] = h;
            ((float4*)pres[cur ^ 1])[tid] = pf0;
        }
        __syncthreads();
        cur ^= 1;
    }
    if (upd) cst[(size_t)(b0 + ub) * 100 + uj] = c;
}

// ---------------------------------------------------------------------------
// rec2 v4 (unchanged this round).
// ---------------------------------------------------------------------------
__global__ __launch_bounds__(256, 4) void rec2(
    const float* __restrict__ pre2,  // [Tc][1024][200]
    const float* __restrict__ Whh,   // [200][50]
    float* __restrict__ cst, float* __restrict__ hst,  // [1024][50]
    float* __restrict__ out,         // [1024][50]
    int Tc, int first)
{
    __shared__ __align__(16) float hs[2][50];
    __shared__ __align__(16) float pres[2][400];
    __shared__ float gbuf[5 * 4 * 2 * 50];
    const int tid = threadIdx.x;
    const int b0 = blockIdx.x * 2;

    const bool comp = tid < 250;
    const int j  = tid % 50;
    const int kq = tid / 50;

    float2 w[4][5];
    if (comp) {
#pragma unroll
        for (int g = 0; g < 4; g++) {
            const float2* W2 = (const float2*)(Whh + (size_t)(g * 50 + j) * 50);
#pragma unroll
            for (int q = 0; q < 5; q++) w[g][q] = W2[kq * 5 + q];
        }
    }

    const bool upd = tid < 100;
    const int ub = tid / 50, uj = tid % 50;
    float c = 0.f, hlast = 0.f;
    if (upd) {
        float h = 0.f;
        if (!first) {
            h = hst[(size_t)(b0 + ub) * 50 + uj];
            c = cst[(size_t)(b0 + ub) * 50 + uj];
        }
        hs[ub][uj] = h;
        hlast = h;
        ((float4*)pres[0])[tid] = ((const float4*)(pre2 + (size_t)b0 * 200))[tid];
    }
    __syncthreads();

    int cur = 0;
    for (int t = 0; t < Tc; t++) {
        int tn = (t + 1 < Tc) ? (t + 1) : t;
        float4 pf0;
        if (upd)
            pf0 = ((const float4*)(pre2 + (size_t)tn * BT * 200 + (size_t)b0 * 200))[tid];

        if (comp) {
            float acc[4][2];
#pragma unroll
            for (int g = 0; g < 4; g++) { acc[g][0] = 0.f; acc[g][1] = 0.f; }
            const float2* hA = (const float2*)hs[0];
            const float2* hB = (const float2*)hs[1];
#pragma unroll
            for (int q = 0; q < 5; q++) {
                int f = kq * 5 + q;
                float2 v0 = hA[f], v1 = hB[f];
#pragma unroll
                for (int g = 0; g < 4; g++) {
                    float2 wq = w[g][q];
                    acc[g][0] = fmaf(wq.x, v0.x, acc[g][0]);
                    acc[g][0] = fmaf(wq.y, v0.y, acc[g][0]);
                    acc[g][1] = fmaf(wq.x, v1.x, acc[g][1]);
                    acc[g][1] = fmaf(wq.y, v1.y, acc[g][1]);
                }
            }
#pragma unroll
            for (int g = 0; g < 4; g++) {
                gbuf[((kq * 4 + g) * 2 + 0) * 50 + j] = acc[g][0];
                gbuf[((kq * 4 + g) * 2 + 1) * 50 + j] = acc[g][1];
            }
        }
        __syncthreads();

        if (upd) {
            const float* pb = pres[cur];
            float s0 = 0.f, s1 = 0.f, s2 = 0.f, s3 = 0.f;
#pragma unroll
            for (int q = 0; q < 5; q++) {
                int base = q * 400;
                s0 += gbuf[base + (0 * 2 + ub) * 50 + uj];
                s1 += gbuf[base + (1 * 2 + ub) * 50 + uj];
                s2 += gbuf[base + (2 * 2 + ub) * 50 + uj];
                s3 += gbuf[base + (3 * 2 + ub) * 50 + uj];
            }
            float xi = s0 + pb[ub * 200 + uj];
            float xf = s1 + pb[ub * 200 + 50 + uj];
            float xg = s2 + pb[ub * 200 + 100 + uj];
            float xo = s3 + pb[ub * 200 + 150 + uj];
            float ii = sig_(xi), ff = sig_(xf), gg = th_(xg), oo = sig_(xo);
            c = ff * c + ii * gg;
            float h = oo * th_(c);
            hs[ub][uj] = h;
            hlast = h;
            ((float4*)pres[cur ^ 1])[tid] = pf0;
        }
        __syncthreads();
        cur ^= 1;
    }
    if (upd) {
        cst[(size_t)(b0 + ub) * 50 + uj] = c;
        hst[(size_t)(b0 + ub) * 50 + uj] = hlast;
        out[(size_t)(b0 + ub) * 50 + uj] = hlast;
    }
}

// ---------------------------------------------------------------------------
extern "C" void kernel_launch(void* const* d_in, const int* in_sizes, int n_in,
                              void* d_out, int out_size, void* d_ws, size_t ws_size,
                              hipStream_t stream)
{
    const float* x    = (const float*)d_in[0];
    const float* Wih1 = (const float*)d_in[1];
    const float* Whh1 = (const float*)d_in[2];
    const float* bih1 = (const float*)d_in[3];
    const float* bhh1 = (const float*)d_in[4];
    const float* Wih2 = (const float*)d_in[5];
    const float* Whh2 = (const float*)d_in[6];
    const float* bih2 = (const float*)d_in[7];
    const float* bhh2 = (const float*)d_in[8];
    float* out = (float*)d_out;
    float* ws  = (float*)d_ws;

    int Tc = 64;
    auto need = [](int tc) -> size_t {
        return ((size_t)tc * 1024 * (400 + 100 + 200) +
                (size_t)1024 * 100 + (size_t)1024 * 50 * 2) * sizeof(float);
    };
    while (Tc > 1 && need(Tc) > ws_size) Tc >>= 1;

    float* pre1 = ws;
    float* h1s  = pre1 + (size_t)Tc * 1024 * 400;
    float* pre2 = h1s  + (size_t)Tc * 1024 * 100;
    float* c1   = pre2 + (size_t)Tc * 1024 * 200;
    float* c2   = c1 + 1024 * 100;
    float* h2st = c2 + 1024 * 50;

    const int nch = TT / Tc;
    for (int ch = 0; ch < nch; ch++) {
        int t0 = ch * Tc;
        // K=80: halves 40+40, LDS 30.7KB -> 4 WGs/CU
        gemm_pre<80, 40, 40, 400, true ><<<dim3(7, Tc * 8), 256, 0, stream>>>(
            x, Wih1, bih1, bhh1, pre1, t0);
        rec1<<<dim3(512), dim3(512), 0, stream>>>(pre1, Whh1, h1s, c1, Tc, ch == 0 ? 1 : 0);
        // K=100: halves 52+48, LDS 39.9KB -> 4 WGs/CU
        gemm_pre<100, 52, 52, 200, false><<<dim3(4, Tc * 8), 256, 0, stream>>>(
            h1s, Wih2, bih2, bhh2, pre2, 0);
        rec2<<<dim3(512), dim3(256), 0, stream>>>(pre2, Whh2, c2, h2st, out, Tc, ch == 0 ? 1 : 0);
    }
}